// Round 9
// baseline (50.246 us; speedup 1.0000x reference)
//
#include <hip/hip_runtime.h>

#define EB_D 128

// Native vector types acceptable to __builtin_nontemporal_load
typedef float fx4 __attribute__((ext_vector_type(4)));
typedef int   ix4 __attribute__((ext_vector_type(4)));

// Kernel 1: rowsum[v] = 5*sum(W0[v,:]) + 10*sum(W1[v,:]) + 6*sum(W2[v,:])
// All-NT loads (round-6 best: ~4.0 TB/s) + two new levers:
//  (a) bijective XCD swizzle (m204): blocks on XCD x (= blockIdx.x%8) cover one
//      CONTIGUOUS ~19 MB row range -> sequential per-XCD DRAM miss stream.
//  (b) 64 rows per 256-thread block: each wave owns 16 rows as 8 pair-steps,
//      24 independent NT float4 loads in flight per thread.
__global__ __launch_bounds__(256) void eb_rowsum_kernel(
    const float* __restrict__ W0,
    const float* __restrict__ W1,
    const float* __restrict__ W2,
    float* __restrict__ rowsum,
    int nrows)
{
    // Bijective XCD-contiguous remap of blockIdx.x (nb need not divide by 8).
    const int nb   = gridDim.x;
    const int q    = nb >> 3;
    const int r    = nb & 7;
    const int xcd  = blockIdx.x & 7;
    const int slot = blockIdx.x >> 3;
    const int swz  = (xcd < r ? xcd * (q + 1) : r * (q + 1) + (xcd - r) * q) + slot;

    const int lane   = threadIdx.x & 63;
    const int wave   = threadIdx.x >> 6;          // 0..3
    const int lane32 = lane & 31;
    const int half   = lane >> 5;                 // 0/1: which row of the pair
    const int rbase  = swz * 64 + wave * 16 + half;   // rows rbase + 2s, s=0..7

    const int vmax = nrows - 1;
    fx4 a[8], b[8], c[8];
    #pragma unroll
    for (int s = 0; s < 8; ++s) {
        int v = rbase + 2 * s;
        v = v < vmax ? v : vmax;                  // clamp OOB loads (last block)
        const size_t base = (size_t)v * EB_D;
        a[s] = __builtin_nontemporal_load((const fx4*)(W0 + base) + lane32);
        b[s] = __builtin_nontemporal_load((const fx4*)(W1 + base) + lane32);
        c[s] = __builtin_nontemporal_load((const fx4*)(W2 + base) + lane32);
    }

    #pragma unroll
    for (int s = 0; s < 8; ++s) {
        float sv = 5.0f  * (a[s].x + a[s].y + a[s].z + a[s].w)
                 + 10.0f * (b[s].x + b[s].y + b[s].z + b[s].w)
                 + 6.0f  * (c[s].x + c[s].y + c[s].z + c[s].w);
        // reduce across the 32 lanes of this half-wave
        #pragma unroll
        for (int m = 16; m >= 1; m >>= 1) sv += __shfl_xor(sv, m, 64);
        const int v = rbase + 2 * s;
        if (lane32 == 0 && v < nrows) rowsum[v] = sv;
    }
}

// Kernel 2: out += sum_i rowsum[idx[i]]  (idx int32); int4-vectorized.
// idx is read-once -> nontemporal; rowsum is hot (400 KB, L2) -> cached.
__global__ __launch_bounds__(256) void eb_gather_reduce_kernel(
    const int* __restrict__ idx,
    const float* __restrict__ rowsum,
    float* __restrict__ out,
    int n4, int n, int nrows)
{
    const int stride = gridDim.x * blockDim.x;
    const ix4* idx4 = (const ix4*)idx;
    float acc = 0.0f;
    for (int i = blockIdx.x * blockDim.x + threadIdx.x; i < n4; i += stride) {
        const ix4 v = __builtin_nontemporal_load(idx4 + i);
        float s0 = ((unsigned)v.x < (unsigned)nrows) ? rowsum[v.x] : 0.0f;
        float s1 = ((unsigned)v.y < (unsigned)nrows) ? rowsum[v.y] : 0.0f;
        float s2 = ((unsigned)v.z < (unsigned)nrows) ? rowsum[v.z] : 0.0f;
        float s3 = ((unsigned)v.w < (unsigned)nrows) ? rowsum[v.w] : 0.0f;
        acc += (s0 + s1) + (s2 + s3);
    }
    // tail (N % 4) — N=819200 divisible by 4, so this is a no-op here
    if (blockIdx.x == 0 && threadIdx.x < (n - n4 * 4)) {
        const int v = idx[n4 * 4 + threadIdx.x];
        if ((unsigned)v < (unsigned)nrows) acc += rowsum[v];
    }

    #pragma unroll
    for (int m = 32; m >= 1; m >>= 1) acc += __shfl_xor(acc, m, 64);

    __shared__ float wsum[4];
    const int lane = threadIdx.x & 63;
    const int wid  = threadIdx.x >> 6;
    if (lane == 0) wsum[wid] = acc;
    __syncthreads();
    if (threadIdx.x == 0) {
        atomicAdd(out, wsum[0] + wsum[1] + wsum[2] + wsum[3]);
    }
}

extern "C" void kernel_launch(void* const* d_in, const int* in_sizes, int n_in,
                              void* d_out, int out_size, void* d_ws, size_t ws_size,
                              hipStream_t stream) {
    const int* eb_input = (const int*)d_in[0];   // int32 indices
    // d_in[1] = eb_offset: mathematically irrelevant (result sums over all bags).
    const float* W0 = (const float*)d_in[2];
    const float* W1 = (const float*)d_in[3];
    const float* W2 = (const float*)d_in[4];

    const int N = in_sizes[0];
    const int nrows = in_sizes[2] / EB_D;   // V = 100000

    float* rowsum = (float*)d_ws;           // V floats = 400 KB
    float* out = (float*)d_out;

    (void)hipMemsetAsync(out, 0, (size_t)out_size * sizeof(float), stream);

    // Kernel 1: 64 rows per block.
    const int blocks1 = (nrows + 63) / 64;  // 1563
    eb_rowsum_kernel<<<blocks1, 256, 0, stream>>>(W0, W1, W2, rowsum, nrows);

    // Kernel 2: vectorized gather-reduce.
    const int n4 = N / 4;
    int blocks2 = (n4 + 255) / 256;
    if (blocks2 > 1024) blocks2 = 1024;
    eb_gather_reduce_kernel<<<blocks2, 256, 0, stream>>>(
        eb_input, rowsum, out, n4, N, nrows);
}

// Round 10
// 41.930 us; speedup vs baseline: 1.1983x; 1.1983x over previous
//
#include <hip/hip_runtime.h>

#define EB_D 128

// Native vector types acceptable to __builtin_nontemporal_load
typedef float fx4 __attribute__((ext_vector_type(4)));
typedef int   ix4 __attribute__((ext_vector_type(4)));

// Kernel 1: rowsum[v] = 5*sum(W0[v,:]) + 10*sum(W1[v,:]) + 6*sum(W2[v,:])
// Round-6 best config: 32 rows per 256-thread block, all loads NONTEMPORAL
// (bypass cache allocation -> ~4.0 TB/s read, vs 3.2 TB/s cached; measured
// invariant across MLP depth 12-24, block geometry, and XCD swizzle).
// Also zeroes d_out (block 0) so no separate memset dispatch is needed:
// gather is stream-ordered after this kernel.
__global__ __launch_bounds__(256) void eb_rowsum_kernel(
    const float* __restrict__ W0,
    const float* __restrict__ W1,
    const float* __restrict__ W2,
    float* __restrict__ rowsum,
    float* __restrict__ out,
    int nrows)
{
    if (blockIdx.x == 0 && threadIdx.x == 0) out[0] = 0.0f;

    const int lane   = threadIdx.x & 63;
    const int wave   = threadIdx.x >> 6;          // 0..3
    const int lane32 = lane & 31;
    const int half   = lane >> 5;                 // 0/1: which row of the pair
    const int rbase  = blockIdx.x * 32 + wave * 8 + half;  // rows rbase+2s, s=0..3

    fx4 a[4], b[4], c[4];
    #pragma unroll
    for (int s = 0; s < 4; ++s) {
        const int v = rbase + 2 * s;
        const size_t base = (size_t)v * EB_D;
        a[s] = __builtin_nontemporal_load((const fx4*)(W0 + base) + lane32);
        b[s] = __builtin_nontemporal_load((const fx4*)(W1 + base) + lane32);
        c[s] = __builtin_nontemporal_load((const fx4*)(W2 + base) + lane32);
    }

    #pragma unroll
    for (int s = 0; s < 4; ++s) {
        float sv = 5.0f  * (a[s].x + a[s].y + a[s].z + a[s].w)
                 + 10.0f * (b[s].x + b[s].y + b[s].z + b[s].w)
                 + 6.0f  * (c[s].x + c[s].y + c[s].z + c[s].w);
        // reduce across the 32 lanes of this half-wave
        #pragma unroll
        for (int m = 16; m >= 1; m >>= 1) sv += __shfl_xor(sv, m, 64);
        const int v = rbase + 2 * s;
        if (lane32 == 0 && v < nrows) rowsum[v] = sv;
    }
}

// Kernel 2: out += sum_i rowsum[idx[i]]  (idx int32); int4-vectorized.
// idx is read-once -> nontemporal; rowsum is hot (400 KB, L2) -> cached.
__global__ __launch_bounds__(256) void eb_gather_reduce_kernel(
    const int* __restrict__ idx,
    const float* __restrict__ rowsum,
    float* __restrict__ out,
    int n4, int n, int nrows)
{
    const int stride = gridDim.x * blockDim.x;
    const ix4* idx4 = (const ix4*)idx;
    float acc = 0.0f;
    for (int i = blockIdx.x * blockDim.x + threadIdx.x; i < n4; i += stride) {
        const ix4 v = __builtin_nontemporal_load(idx4 + i);
        float s0 = ((unsigned)v.x < (unsigned)nrows) ? rowsum[v.x] : 0.0f;
        float s1 = ((unsigned)v.y < (unsigned)nrows) ? rowsum[v.y] : 0.0f;
        float s2 = ((unsigned)v.z < (unsigned)nrows) ? rowsum[v.z] : 0.0f;
        float s3 = ((unsigned)v.w < (unsigned)nrows) ? rowsum[v.w] : 0.0f;
        acc += (s0 + s1) + (s2 + s3);
    }
    // tail (N % 4) — N=819200 divisible by 4, so this is a no-op here
    if (blockIdx.x == 0 && threadIdx.x < (n - n4 * 4)) {
        const int v = idx[n4 * 4 + threadIdx.x];
        if ((unsigned)v < (unsigned)nrows) acc += rowsum[v];
    }

    #pragma unroll
    for (int m = 32; m >= 1; m >>= 1) acc += __shfl_xor(acc, m, 64);

    __shared__ float wsum[4];
    const int lane = threadIdx.x & 63;
    const int wid  = threadIdx.x >> 6;
    if (lane == 0) wsum[wid] = acc;
    __syncthreads();
    if (threadIdx.x == 0) {
        atomicAdd(out, wsum[0] + wsum[1] + wsum[2] + wsum[3]);
    }
}

extern "C" void kernel_launch(void* const* d_in, const int* in_sizes, int n_in,
                              void* d_out, int out_size, void* d_ws, size_t ws_size,
                              hipStream_t stream) {
    const int* eb_input = (const int*)d_in[0];   // int32 indices
    // d_in[1] = eb_offset: mathematically irrelevant (result sums over all bags).
    const float* W0 = (const float*)d_in[2];
    const float* W1 = (const float*)d_in[3];
    const float* W2 = (const float*)d_in[4];

    const int N = in_sizes[0];
    const int nrows = in_sizes[2] / EB_D;   // V = 100000

    float* rowsum = (float*)d_ws;           // V floats = 400 KB
    float* out = (float*)d_out;

    // Kernel 1: 32 rows per block; also zeroes out[0] (no memset dispatch).
    const int blocks1 = (nrows + 31) / 32;  // 3125
    eb_rowsum_kernel<<<blocks1, 256, 0, stream>>>(W0, W1, W2, rowsum, out, nrows);

    // Kernel 2: vectorized gather-reduce.
    const int n4 = N / 4;
    int blocks2 = (n4 + 255) / 256;
    if (blocks2 > 1024) blocks2 = 1024;
    eb_gather_reduce_kernel<<<blocks2, 256, 0, stream>>>(
        eb_input, rowsum, out, n4, N, nrows);
}